// Round 11
// baseline (4803.798 us; speedup 1.0000x reference)
//
#include <hip/hip_runtime.h>

#define T_TOK 8192   // B*S tokens
#define HDIM  2048
#define IDIM  8192
#define KKEEP 4096
#define TCHK  2048   // token chunk (U parks in d_out)
#define BAND  2.5e-3f
#define MAXB  192

typedef _Float16 f16x8 __attribute__((ext_vector_type(8)));
typedef float    f32x4 __attribute__((ext_vector_type(4)));

#define AS1 __attribute__((address_space(1)))
#define AS3 __attribute__((address_space(3)))
#define BARR asm volatile("s_barrier" ::: "memory")

// LDS permutation for 64-B rows (BK=32): bits[4:5] ^= bits[7:8], bit[6] ^= bit[8].
__device__ __forceinline__ int swz(int b) {
    return b ^ ((b >> 3) & 0x30) ^ ((b >> 2) & 0x40);
}

union H16 { ushort u; _Float16 h; };

// ---------------- cast ----------------

__global__ void cast_f16(const float4* __restrict__ in, ushort4* __restrict__ o, long n4) {
    long stride = (long)gridDim.x * blockDim.x;
    for (long i = (long)blockIdx.x * blockDim.x + threadIdx.x; i < n4; i += stride) {
        float4 v = in[i];
        float vv[4] = {v.x, v.y, v.z, v.w};
        union { _Float16 f[4]; ushort4 u; } H;
        #pragma unroll
        for (int j = 0; j < 4; ++j) H.f[j] = (_Float16)vv[j];
        o[i] = H.u;
    }
}

// -------- FUSED dual-B GEMM: G = A@Bg^T, U = A@Bu^T (f16 out), BK=32, 3-deep --------

#define GLOAD(src_, dst_) \
    __builtin_amdgcn_global_load_lds((const AS1 void*)(src_), (AS3 void*)(dst_), 16, 0, 0)

#define STAGE6(kt_, buf_) do { \
    char* db_ = Lc + (buf_)*49152 + wave*1024; \
    GLOAD(A0 + aBase + (kt_) + off0, db_); \
    GLOAD(A0 + aBase + (kt_) + off1, db_ + 8192); \
    GLOAD(Bg + bBase + (kt_) + off2, db_ + 16384); \
    GLOAD(Bg + bBase + (kt_) + off3, db_ + 24576); \
    GLOAD(Bu + bBase + (kt_) + off4, db_ + 32768); \
    GLOAD(Bu + bBase + (kt_) + off5, db_ + 40960); \
  } while (0)

__global__ __launch_bounds__(512, 2) void gemmF(
    const _Float16* __restrict__ A0, const _Float16* __restrict__ Bg,
    const _Float16* __restrict__ Bu, int N, int Kp,
    _Float16* __restrict__ Gout, _Float16* __restrict__ Uout)
{
    __shared__ __align__(128) char Lc[147456];   // 3 bufs x 48KB (A|Bg|Bu)
    const int tid  = threadIdx.x;
    const int lane = tid & 63;
    const int wave = tid >> 6;
    const int wr = wave >> 2, wc = wave & 3;     // wave tile 128x64

    // XCD-bijective block swizzle
    const int gx = gridDim.x, gy = gridDim.y;
    const int nwg = gx * gy;
    const int orig = blockIdx.y * gx + blockIdx.x;
    const int q = nwg >> 3, r = nwg & 7, xcd = orig & 7, lid = orig >> 3;
    const int wg = (xcd < r ? xcd * (q + 1) : r * (q + 1) + (xcd - r) * q) + lid;
    const int bm = wg / gy, bn = wg % gy;

    // staging map: linear LDS dest <- inverse-swizzled global source
    int off0, off1, off2, off3, off4, off5;
    {
        int o[6];
        #pragma unroll
        for (int g = 0; g < 6; ++g) {
            int p = g * 8192 + tid * 16;
            int l = swz(p);
            int row = (l >> 6) & 255;
            int col = (l & 63) >> 1;
            o[g] = row * Kp + col;
        }
        off0 = o[0]; off1 = o[1]; off2 = o[2]; off3 = o[3]; off4 = o[4]; off5 = o[5];
    }
    const size_t aBase = (size_t)bm * 256 * Kp;
    const size_t bBase = (size_t)bn * 256 * Kp;

    const int l15 = lane & 15, lhi = lane >> 4;
    const int pa  = swz((wr * 128 + l15) * 64 + lhi * 16);
    const int pbg = swz(16384 + (wc * 64 + l15) * 64 + lhi * 16);
    const int pbu = swz(32768 + (wc * 64 + l15) * 64 + lhi * 16);

    const int NT = Kp >> 5;

    f32x4 accG[8][4] = {}, accU[8][4] = {};

    STAGE6(0,  0);
    STAGE6(32, 1);

    int bsel = 0;
    for (int t = 0; t < NT; ++t) {
        asm volatile("s_waitcnt lgkmcnt(0)" ::: "memory");
        if (t < NT - 1) asm volatile("s_waitcnt vmcnt(6)" ::: "memory");
        else            asm volatile("s_waitcnt vmcnt(0)" ::: "memory");
        BARR;

        const char* bp = Lc + bsel * 49152;
        f16x8 af[8], bgf[4], buf_[4];
        #pragma unroll
        for (int m = 0; m < 8; ++m) af[m]   = *(const f16x8*)(bp + pa  + m * 1024);
        #pragma unroll
        for (int n = 0; n < 4; ++n) bgf[n]  = *(const f16x8*)(bp + pbg + n * 1024);
        #pragma unroll
        for (int n = 0; n < 4; ++n) buf_[n] = *(const f16x8*)(bp + pbu + n * 1024);

        if (t + 2 < NT) {
            int bs2 = bsel + 2; if (bs2 >= 3) bs2 -= 3;
            STAGE6((t + 2) << 5, bs2);
        }

        asm volatile("s_waitcnt lgkmcnt(0)" ::: "memory");
        __builtin_amdgcn_sched_barrier(0);
        __builtin_amdgcn_s_setprio(1);
        #pragma unroll
        for (int m = 0; m < 8; ++m)
            #pragma unroll
            for (int n = 0; n < 4; ++n) {
                accG[m][n] = __builtin_amdgcn_mfma_f32_16x16x32_f16(af[m], bgf[n],  accG[m][n], 0, 0, 0);
                accU[m][n] = __builtin_amdgcn_mfma_f32_16x16x32_f16(af[m], buf_[n], accU[m][n], 0, 0, 0);
            }
        __builtin_amdgcn_s_setprio(0);
        ++bsel; if (bsel >= 3) bsel = 0;
    }

    const int r0 = bm * 256 + wr * 128 + (lane >> 4) * 4;
    const int c0 = bn * 256 + wc * 64 + (lane & 15);
    #pragma unroll
    for (int m = 0; m < 8; ++m) {
        #pragma unroll
        for (int n = 0; n < 4; ++n) {
            #pragma unroll
            for (int rr = 0; rr < 4; ++rr) {
                const size_t idx = (size_t)(r0 + m * 16 + rr) * N + (c0 + n * 16);
                Gout[idx] = (_Float16)accG[m][n][rr];
                Uout[idx] = (_Float16)accU[m][n][rr];
            }
        }
    }
}

// ------- 256x256 GEMM, BK=32, 4-deep (R10 structure) — used for DOWN -------

#define STAGE4(pA_, pB_, kt_, buf_) do { \
    char* db_ = Lc + (buf_)*32768 + wave*1024; \
    GLOAD((pA_) + aBase + (kt_) + off0, db_); \
    GLOAD((pA_) + aBase + (kt_) + off1, db_ +  8192); \
    GLOAD((pB_) + bBase + (kt_) + off2, db_ + 16384); \
    GLOAD((pB_) + bBase + (kt_) + off3, db_ + 24576); \
  } while (0)

__global__ __launch_bounds__(512, 2) void gemmD(
    const _Float16* __restrict__ A0, const _Float16* __restrict__ B0,
    int N, int Kp, float* __restrict__ Cf)
{
    __shared__ __align__(128) char Lc[131072];
    const int tid  = threadIdx.x;
    const int lane = tid & 63;
    const int wave = tid >> 6;
    const int wr = wave >> 2, wc = wave & 3;

    const int gx = gridDim.x, gy = gridDim.y;
    const int nwg = gx * gy;
    const int orig = blockIdx.y * gx + blockIdx.x;
    const int q = nwg >> 3, r = nwg & 7, xcd = orig & 7, lid = orig >> 3;
    const int wg = (xcd < r ? xcd * (q + 1) : r * (q + 1) + (xcd - r) * q) + lid;
    const int bm = wg / gy, bn = wg % gy;

    int off0, off1, off2, off3;
    {
        int o[4];
        #pragma unroll
        for (int g = 0; g < 4; ++g) {
            int p = g * 8192 + tid * 16;
            int l = swz(p);
            int row = (l >> 6) & 255;
            int col = (l & 63) >> 1;
            o[g] = row * Kp + col;
        }
        off0 = o[0]; off1 = o[1]; off2 = o[2]; off3 = o[3];
    }
    const size_t aBase = (size_t)bm * 256 * Kp;
    const size_t bBase = (size_t)bn * 256 * Kp;

    const int l15 = lane & 15, lhi = lane >> 4;
    const int pa = swz((wr * 128 + l15) * 64 + lhi * 16);
    const int pb = swz(16384 + (wc * 64 + l15) * 64 + lhi * 16);

    const int NT = Kp >> 5;
    f32x4 acc[8][4] = {};

    STAGE4(A0, B0, 0,  0);
    STAGE4(A0, B0, 32, 1);
    STAGE4(A0, B0, 64, 2);

    for (int t = 0; t < NT; ++t) {
        const int rem = NT - t;
        asm volatile("s_waitcnt lgkmcnt(0)" ::: "memory");
        if (rem >= 3)      asm volatile("s_waitcnt vmcnt(8)" ::: "memory");
        else if (rem == 2) asm volatile("s_waitcnt vmcnt(4)" ::: "memory");
        else               asm volatile("s_waitcnt vmcnt(0)" ::: "memory");
        BARR;

        const char* bp = Lc + (t & 3) * 32768;
        f16x8 af[8], bfv[4];
        #pragma unroll
        for (int m = 0; m < 8; ++m) af[m]  = *(const f16x8*)(bp + pa + m * 1024);
        #pragma unroll
        for (int n = 0; n < 4; ++n) bfv[n] = *(const f16x8*)(bp + pb + n * 1024);

        if (t + 3 < NT) STAGE4(A0, B0, (t + 3) << 5, (t + 3) & 3);

        asm volatile("s_waitcnt lgkmcnt(0)" ::: "memory");
        __builtin_amdgcn_sched_barrier(0);
        __builtin_amdgcn_s_setprio(1);
        #pragma unroll
        for (int m = 0; m < 8; ++m)
            #pragma unroll
            for (int n = 0; n < 4; ++n)
                acc[m][n] = __builtin_amdgcn_mfma_f32_16x16x32_f16(af[m], bfv[n], acc[m][n], 0, 0, 0);
        __builtin_amdgcn_s_setprio(0);
    }

    const int r0 = bm * 256 + wr * 128 + (lane >> 4) * 4;
    const int c0 = bn * 256 + wc * 64 + (lane & 15);
    #pragma unroll
    for (int m = 0; m < 8; ++m)
        #pragma unroll
        for (int n = 0; n < 4; ++n)
            #pragma unroll
            for (int rr = 0; rr < 4; ++rr)
                Cf[(size_t)(r0 + m * 16 + rr) * N + (c0 + n * 16)] = acc[m][n][rr];
}

// ---- topk + exact band-recompute + fused P = mask * g * u (in place over G) ----

__global__ __launch_bounds__(256) void topk_sel(
    _Float16* __restrict__ GP,        // chunk base of G; becomes P in place
    const _Float16* __restrict__ U,   // chunk U
    const float* __restrict__ xf,     // chunk base of f32 x
    const float* __restrict__ Wgf)    // full f32 Wg [I][H]
{
    __shared__ ushort keys[IDIM];          // |g| f16 bits
    __shared__ float  xrow[HDIM];
    __shared__ unsigned char bmap[IDIM];
    __shared__ unsigned hist[256], sA_[256], sB_[256];
    __shared__ unsigned selBin, selAbove;
    __shared__ int Acnt, nbv;
    __shared__ int   bidxs[MAXB];
    __shared__ float bval[MAXB];
    __shared__ int   kflag[MAXB];

    const int tid = threadIdx.x;
    const int t = blockIdx.x;
    _Float16* grow = GP + (size_t)t * IDIM;
    const _Float16* urow = U + (size_t)t * IDIM;

    if (tid == 0) { Acnt = 0; nbv = 0; }
    for (int j = tid; j < IDIM; j += 256) {
        H16 c; c.h = grow[j];
        keys[j] = (ushort)(c.u & 0x7FFFu);
        bmap[j] = 255;
    }
    __syncthreads();

    // 2-pass radix select: kq = f16 bits of K-th largest |g|
    unsigned kq = 0;
    int Krem = KKEEP;
    for (int pass = 0; pass < 2; ++pass) {
        const int shift = pass == 0 ? 7 : 0;
        const unsigned msk = pass == 0 ? 255u : 127u;
        hist[tid] = 0;
        __syncthreads();
        for (int j = tid; j < IDIM; j += 256) {
            unsigned k = keys[j];
            bool ok = (pass == 0) || ((k >> 7) == (kq >> 7));
            if (ok) atomicAdd(&hist[(k >> shift) & msk], 1u);
        }
        __syncthreads();
        sA_[tid] = hist[tid];
        __syncthreads();
        unsigned *src = sA_, *dst = sB_;
        for (int off = 1; off < 256; off <<= 1) {
            unsigned v = src[tid] + ((tid + off < 256) ? src[tid + off] : 0u);
            dst[tid] = v;
            __syncthreads();
            unsigned* tmp = src; src = dst; dst = tmp;
        }
        unsigned S  = src[tid];
        unsigned Sn = (tid < 255) ? src[tid + 1] : 0u;
        if ((int)S >= Krem && (int)Sn < Krem) { selBin = (unsigned)tid; selAbove = Sn; }
        __syncthreads();
        kq |= selBin << shift;
        Krem -= (int)selAbove;
        __syncthreads();
    }
    H16 cv; cv.u = (ushort)kq;
    const float kthf = (float)cv.h;
    const float hif = kthf + BAND;
    const float lof = kthf - BAND;

    // count above-band, collect band members
    for (int j = tid; j < IDIM; j += 256) {
        H16 c; c.u = keys[j];
        float v = (float)c.h;
        if (v > hif) atomicAdd(&Acnt, 1);
        else if (v >= lof) {
            int s = atomicAdd(&nbv, 1);
            if (s < MAXB) { bidxs[s] = j; bmap[j] = (unsigned char)s; }
        }
    }
    // x row -> LDS
    for (int j = tid; j < HDIM; j += 256) xrow[j] = xf[(size_t)t * HDIM + j];
    __syncthreads();

    const int nbc = nbv < MAXB ? nbv : MAXB;
    int R = KKEEP - Acnt;
    R = R < 0 ? 0 : (R > nbc ? nbc : R);

    // exact f32 dots for band members (one wave per member)
    const int wv = tid >> 6, ln = tid & 63;
    for (int j = wv; j < nbc; j += 4) {
        const float* wrow = Wgf + (size_t)bidxs[j] * HDIM;
        float s = 0.f;
        #pragma unroll 4
        for (int it = 0; it < HDIM / 64; ++it) {
            int c = it * 64 + ln;
            s = fmaf(xrow[c], wrow[c], s);
        }
        #pragma unroll
        for (int o = 32; o; o >>= 1) s += __shfl_xor(s, o);
        if (ln == 0) bval[j] = fabsf(s);
    }
    __syncthreads();

    // keep the R largest exact band values (ties -> all kept, matching >= semantics)
    for (int j = tid; j < nbc; j += 256) {
        int rk = 0;
        float vj = bval[j];
        for (int k = 0; k < nbc; ++k) rk += (bval[k] > vj);
        kflag[j] = (rk < R) ? 1 : 0;
    }
    __syncthreads();

    // write P = keep ? g*u : 0
    for (int j = tid; j < IDIM; j += 256) {
        float g = (float)grow[j];
        float v = fabsf(g);
        bool keep;
        unsigned char s = bmap[j];
        if (s != 255)      keep = (kflag[s] != 0);
        else if (v > hif)  keep = true;
        else if (v < lof)  keep = false;
        else               keep = (v >= kthf);   // band overflow fallback (rare)
        float u = (float)urow[j];
        grow[j] = keep ? (_Float16)(g * u) : (_Float16)0.f;
    }
}

// ---------------- host ----------------

extern "C" void kernel_launch(void* const* d_in, const int* in_sizes, int n_in,
                              void* d_out, int out_size, void* d_ws, size_t ws_size,
                              hipStream_t stream) {
    const float* x  = (const float*)d_in[0];   // [T,H]
    const float* Wg = (const float*)d_in[1];   // [I,H]
    const float* Wu = (const float*)d_in[2];   // [I,H]
    const float* Wd = (const float*)d_in[3];   // [H,I]

    const size_t NE   = (size_t)T_TOK * HDIM;  // 16.8M
    const size_t szH2 = NE * 2;                // 33.55 MB

    char* ws = (char*)d_ws;
    _Float16* xh   = (_Float16*)ws;
    _Float16* Wgh  = (_Float16*)(ws + szH2);
    _Float16* Wu16 = (_Float16*)(ws + 2 * szH2);
    _Float16* Wd16 = (_Float16*)(ws + 3 * szH2);
    _Float16* G    = (_Float16*)(ws + 4 * szH2);   // [T][I] f16 gate -> P in place
    _Float16* Uc   = (_Float16*)d_out;             // per-chunk U (33.5MB in 67MB d_out)

    const long n4 = (long)(NE / 4);
    cast_f16<<<1024, 256, 0, stream>>>((const float4*)x,  (ushort4*)xh,   n4);
    cast_f16<<<1024, 256, 0, stream>>>((const float4*)Wg, (ushort4*)Wgh,  n4);
    cast_f16<<<1024, 256, 0, stream>>>((const float4*)Wu, (ushort4*)Wu16, n4);
    cast_f16<<<1024, 256, 0, stream>>>((const float4*)Wd, (ushort4*)Wd16, n4);

    for (int c0 = 0; c0 < T_TOK; c0 += TCHK) {
        gemmF<<<dim3(TCHK / 256, IDIM / 256), 512, 0, stream>>>(
            xh + (size_t)c0 * HDIM, Wgh, Wu16, IDIM, HDIM,
            G + (size_t)c0 * IDIM, Uc);
        topk_sel<<<TCHK, 256, 0, stream>>>(
            G + (size_t)c0 * IDIM, Uc, x + (size_t)c0 * HDIM, Wg);
    }

    // DOWN: out = P @ Wd^T  (overwrites d_out after all U chunks consumed)
    gemmD<<<dim3(T_TOK / 256, HDIM / 256), 512, 0, stream>>>(
        G, Wd16, HDIM, IDIM, (float*)d_out);
}

// Round 12
// 1512.226 us; speedup vs baseline: 3.1766x; 3.1766x over previous
//
#include <hip/hip_runtime.h>

#define T_TOK 8192   // B*S tokens
#define HDIM  2048
#define IDIM  8192
#define KKEEP 4096
#define TCHK  4096   // token chunk for UP (U parks in d_out, 67 MB)
#define BAND  2.5e-3f
#define MAXB  192

typedef _Float16 f16x8 __attribute__((ext_vector_type(8)));
typedef float    f32x4 __attribute__((ext_vector_type(4)));

#define AS1 __attribute__((address_space(1)))
#define AS3 __attribute__((address_space(3)))
#define BARR asm volatile("s_barrier" ::: "memory")

// LDS permutation for 64-B rows (BK=32): bits[4:5] ^= bits[7:8], bit[6] ^= bit[8].
__device__ __forceinline__ int swz(int b) {
    return b ^ ((b >> 3) & 0x30) ^ ((b >> 2) & 0x40);
}

union H16 { ushort u; _Float16 h; };

// ---------------- cast ----------------

__global__ void cast_f16(const float4* __restrict__ in, ushort4* __restrict__ o, long n4) {
    long stride = (long)gridDim.x * blockDim.x;
    for (long i = (long)blockIdx.x * blockDim.x + threadIdx.x; i < n4; i += stride) {
        float4 v = in[i];
        float vv[4] = {v.x, v.y, v.z, v.w};
        union { _Float16 f[4]; ushort4 u; } H;
        #pragma unroll
        for (int j = 0; j < 4; ++j) H.f[j] = (_Float16)vv[j];
        o[i] = H.u;
    }
}

// ------- 256x256 GEMM, BK=32, 4-deep LDS pipeline (R10-proven core) -------
// MODE 0: f32 out (DOWN)   MODE 1: f16 out (GATE, UP)

#define GLOAD(src_, dst_) \
    __builtin_amdgcn_global_load_lds((const AS1 void*)(src_), (AS3 void*)(dst_), 16, 0, 0)

#define STAGE4(pA_, pB_, kt_, buf_) do { \
    char* db_ = Lc + (buf_)*32768 + wave*1024; \
    GLOAD((pA_) + aBase + (kt_) + off0, db_); \
    GLOAD((pA_) + aBase + (kt_) + off1, db_ +  8192); \
    GLOAD((pB_) + bBase + (kt_) + off2, db_ + 16384); \
    GLOAD((pB_) + bBase + (kt_) + off3, db_ + 24576); \
  } while (0)

template <int MODE>
__global__ __launch_bounds__(512, 2) void gemm4(
    const _Float16* __restrict__ A0, const _Float16* __restrict__ B0,
    int N, int Kp, float* __restrict__ Cf, _Float16* __restrict__ Ch)
{
    __shared__ __align__(128) char Lc[131072];   // 4 bufs x 32 KB (A 16K | B 16K)
    const int tid  = threadIdx.x;
    const int lane = tid & 63;
    const int wave = tid >> 6;
    const int wr = wave >> 2, wc = wave & 3;     // wave tile 128x64

    // XCD-bijective block swizzle
    const int gx = gridDim.x, gy = gridDim.y;
    const int nwg = gx * gy;
    const int orig = blockIdx.y * gx + blockIdx.x;
    const int q = nwg >> 3, r = nwg & 7, xcd = orig & 7, lid = orig >> 3;
    const int wg = (xcd < r ? xcd * (q + 1) : r * (q + 1) + (xcd - r) * q) + lid;
    const int bm = wg / gy, bn = wg % gy;

    // staging map: linear LDS dest (tid*16) <- inverse-swizzled global source
    int off0, off1, off2, off3;
    {
        int o[4];
        #pragma unroll
        for (int g = 0; g < 4; ++g) {
            int p = g * 8192 + tid * 16;
            int l = swz(p);
            int row = (l >> 6) & 255;
            int col = (l & 63) >> 1;
            o[g] = row * Kp + col;
        }
        off0 = o[0]; off1 = o[1]; off2 = o[2]; off3 = o[3];
    }
    const size_t aBase = (size_t)bm * 256 * Kp;
    const size_t bBase = (size_t)bn * 256 * Kp;

    const int l15 = lane & 15, lhi = lane >> 4;
    const int pa = swz((wr * 128 + l15) * 64 + lhi * 16);
    const int pb = swz(16384 + (wc * 64 + l15) * 64 + lhi * 16);

    const int NT = Kp >> 5;
    f32x4 acc[8][4] = {};

    // prologue: stage tiles 0,1,2 (12 loads in flight)
    STAGE4(A0, B0, 0,  0);
    STAGE4(A0, B0, 32, 1);
    STAGE4(A0, B0, 64, 2);

    for (int t = 0; t < NT; ++t) {
        const int rem = NT - t;
        asm volatile("s_waitcnt lgkmcnt(0)" ::: "memory");
        if (rem >= 3)      asm volatile("s_waitcnt vmcnt(8)" ::: "memory");
        else if (rem == 2) asm volatile("s_waitcnt vmcnt(4)" ::: "memory");
        else               asm volatile("s_waitcnt vmcnt(0)" ::: "memory");
        BARR;

        const char* bp = Lc + (t & 3) * 32768;
        f16x8 af[8], bfv[4];
        #pragma unroll
        for (int m = 0; m < 8; ++m) af[m]  = *(const f16x8*)(bp + pa + m * 1024);
        #pragma unroll
        for (int n = 0; n < 4; ++n) bfv[n] = *(const f16x8*)(bp + pb + n * 1024);

        if (t + 3 < NT) STAGE4(A0, B0, (t + 3) << 5, (t + 3) & 3);

        asm volatile("s_waitcnt lgkmcnt(0)" ::: "memory");
        __builtin_amdgcn_sched_barrier(0);
        __builtin_amdgcn_s_setprio(1);
        #pragma unroll
        for (int m = 0; m < 8; ++m)
            #pragma unroll
            for (int n = 0; n < 4; ++n)
                acc[m][n] = __builtin_amdgcn_mfma_f32_16x16x32_f16(af[m], bfv[n], acc[m][n], 0, 0, 0);
        __builtin_amdgcn_s_setprio(0);
    }

    // epilogue; C/D layout: col = lane&15, row = (lane>>4)*4 + reg
    const int r0 = bm * 256 + wr * 128 + (lane >> 4) * 4;
    const int c0 = bn * 256 + wc * 64 + (lane & 15);
    #pragma unroll
    for (int m = 0; m < 8; ++m) {
        #pragma unroll
        for (int n = 0; n < 4; ++n) {
            #pragma unroll
            for (int rr = 0; rr < 4; ++rr) {
                const size_t idx = (size_t)(r0 + m * 16 + rr) * N + (c0 + n * 16);
                if (MODE == 0) Cf[idx] = acc[m][n][rr];
                else           Ch[idx] = (_Float16)acc[m][n][rr];
            }
        }
    }
}

// ---- topk + exact band-recompute + fused P = mask * g * u (in place over G) ----

__global__ __launch_bounds__(256) void topk_sel(
    _Float16* __restrict__ GP,        // chunk base of G; becomes P in place
    const _Float16* __restrict__ U,   // chunk U
    const float* __restrict__ xf,     // chunk base of f32 x
    const float* __restrict__ Wgf)    // full f32 Wg [I][H]
{
    __shared__ ushort keys[IDIM];          // |g| f16 bits
    __shared__ float  xrow[HDIM];
    __shared__ unsigned char bmap[IDIM];
    __shared__ unsigned hist[256], sA_[256], sB_[256];
    __shared__ unsigned selBin, selAbove;
    __shared__ int Acnt, nbv;
    __shared__ int   bidxs[MAXB];
    __shared__ float bval[MAXB];
    __shared__ int   kflag[MAXB];

    const int tid = threadIdx.x;
    const int t = blockIdx.x;
    _Float16* grow = GP + (size_t)t * IDIM;
    const _Float16* urow = U + (size_t)t * IDIM;

    if (tid == 0) { Acnt = 0; nbv = 0; }
    for (int j = tid; j < IDIM; j += 256) {
        H16 c; c.h = grow[j];
        keys[j] = (ushort)(c.u & 0x7FFFu);
        bmap[j] = 255;
    }
    __syncthreads();

    // 2-pass radix select: kq = f16 bits of K-th largest |g|
    unsigned kq = 0;
    int Krem = KKEEP;
    for (int pass = 0; pass < 2; ++pass) {
        const int shift = pass == 0 ? 7 : 0;
        const unsigned msk = pass == 0 ? 255u : 127u;
        hist[tid] = 0;
        __syncthreads();
        for (int j = tid; j < IDIM; j += 256) {
            unsigned k = keys[j];
            bool ok = (pass == 0) || ((k >> 7) == (kq >> 7));
            if (ok) atomicAdd(&hist[(k >> shift) & msk], 1u);
        }
        __syncthreads();
        sA_[tid] = hist[tid];
        __syncthreads();
        unsigned *src = sA_, *dst = sB_;
        for (int off = 1; off < 256; off <<= 1) {
            unsigned v = src[tid] + ((tid + off < 256) ? src[tid + off] : 0u);
            dst[tid] = v;
            __syncthreads();
            unsigned* tmp = src; src = dst; dst = tmp;
        }
        unsigned S  = src[tid];
        unsigned Sn = (tid < 255) ? src[tid + 1] : 0u;
        if ((int)S >= Krem && (int)Sn < Krem) { selBin = (unsigned)tid; selAbove = Sn; }
        __syncthreads();
        kq |= selBin << shift;
        Krem -= (int)selAbove;
        __syncthreads();
    }
    H16 cv; cv.u = (ushort)kq;
    const float kthf = (float)cv.h;
    const float hif = kthf + BAND;
    const float lof = kthf - BAND;

    // count above-band, collect band members
    for (int j = tid; j < IDIM; j += 256) {
        H16 c; c.u = keys[j];
        float v = (float)c.h;
        if (v > hif) atomicAdd(&Acnt, 1);
        else if (v >= lof) {
            int s = atomicAdd(&nbv, 1);
            if (s < MAXB) { bidxs[s] = j; bmap[j] = (unsigned char)s; }
        }
    }
    // x row -> LDS
    for (int j = tid; j < HDIM; j += 256) xrow[j] = xf[(size_t)t * HDIM + j];
    __syncthreads();

    const int nbc = nbv < MAXB ? nbv : MAXB;
    int R = KKEEP - Acnt;
    R = R < 0 ? 0 : (R > nbc ? nbc : R);

    // exact f32 dots for band members (one wave per member)
    const int wv = tid >> 6, ln = tid & 63;
    for (int j = wv; j < nbc; j += 4) {
        const float* wrow = Wgf + (size_t)bidxs[j] * HDIM;
        float s = 0.f;
        #pragma unroll 4
        for (int it = 0; it < HDIM / 64; ++it) {
            int c = it * 64 + ln;
            s = fmaf(xrow[c], wrow[c], s);
        }
        #pragma unroll
        for (int o = 32; o; o >>= 1) s += __shfl_xor(s, o);
        if (ln == 0) bval[j] = fabsf(s);
    }
    __syncthreads();

    // keep the R largest exact band values
    for (int j = tid; j < nbc; j += 256) {
        int rk = 0;
        float vj = bval[j];
        for (int k = 0; k < nbc; ++k) rk += (bval[k] > vj);
        kflag[j] = (rk < R) ? 1 : 0;
    }
    __syncthreads();

    // write P = keep ? g*u : 0
    for (int j = tid; j < IDIM; j += 256) {
        float g = (float)grow[j];
        float v = fabsf(g);
        bool keep;
        unsigned char s = bmap[j];
        if (s != 255)      keep = (kflag[s] != 0);
        else if (v > hif)  keep = true;
        else if (v < lof)  keep = false;
        else               keep = (v >= kthf);   // band overflow fallback (rare)
        float u = (float)urow[j];
        grow[j] = keep ? (_Float16)(g * u) : (_Float16)0.f;
    }
}

// ---------------- host ----------------

extern "C" void kernel_launch(void* const* d_in, const int* in_sizes, int n_in,
                              void* d_out, int out_size, void* d_ws, size_t ws_size,
                              hipStream_t stream) {
    const float* x  = (const float*)d_in[0];   // [T,H]
    const float* Wg = (const float*)d_in[1];   // [I,H]
    const float* Wu = (const float*)d_in[2];   // [I,H]
    const float* Wd = (const float*)d_in[3];   // [H,I]

    const size_t NE   = (size_t)T_TOK * HDIM;  // 16.8M
    const size_t szH2 = NE * 2;                // 33.55 MB

    char* ws = (char*)d_ws;
    _Float16* xh   = (_Float16*)ws;
    _Float16* Wgh  = (_Float16*)(ws + szH2);
    _Float16* Wu16 = (_Float16*)(ws + 2 * szH2);
    _Float16* Wd16 = (_Float16*)(ws + 3 * szH2);
    _Float16* G    = (_Float16*)(ws + 4 * szH2);   // [T][I] f16 gate -> P in place (134 MB)
    _Float16* Uc   = (_Float16*)d_out;             // per-chunk U (67 MB)

    const long n4 = (long)(NE / 4);
    cast_f16<<<1024, 256, 0, stream>>>((const float4*)x,  (ushort4*)xh,   n4);
    cast_f16<<<1024, 256, 0, stream>>>((const float4*)Wg, (ushort4*)Wgh,  n4);
    cast_f16<<<1024, 256, 0, stream>>>((const float4*)Wu, (ushort4*)Wu16, n4);
    cast_f16<<<1024, 256, 0, stream>>>((const float4*)Wd, (ushort4*)Wd16, n4);

    // GATE: full-size 1-pass f16 gate
    gemm4<1><<<dim3(T_TOK / 256, IDIM / 256), 512, 0, stream>>>(
        xh, Wgh, IDIM, HDIM, nullptr, G);

    // per chunk: UP -> Uc; selection + P = mask*g*u in place over G
    for (int c0 = 0; c0 < T_TOK; c0 += TCHK) {
        gemm4<1><<<dim3(TCHK / 256, IDIM / 256), 512, 0, stream>>>(
            xh + (size_t)c0 * HDIM, Wu16, IDIM, HDIM, nullptr, Uc);
        topk_sel<<<TCHK, 256, 0, stream>>>(
            G + (size_t)c0 * IDIM, Uc, x + (size_t)c0 * HDIM, Wg);
    }

    // DOWN: out = P @ Wd^T (overwrites d_out after all U chunks consumed)
    gemm4<0><<<dim3(T_TOK / 256, HDIM / 256), 512, 0, stream>>>(
        G, Wd16, HDIM, IDIM, (float*)d_out, nullptr);
}

// Round 13
// 1459.421 us; speedup vs baseline: 3.2916x; 1.0362x over previous
//
#include <hip/hip_runtime.h>

#define T_TOK 8192   // B*S tokens
#define HDIM  2048
#define IDIM  8192
#define KKEEP 4096
#define TCHK  4096   // token chunk for UP (U parks in d_out, 67 MB)
#define BAND  1.6e-3f
#define MAXB  192

typedef _Float16 f16x8 __attribute__((ext_vector_type(8)));
typedef float    f32x4 __attribute__((ext_vector_type(4)));

#define AS1 __attribute__((address_space(1)))
#define AS3 __attribute__((address_space(3)))
#define BARR asm volatile("s_barrier" ::: "memory")

// swizzle for 64-B rows (BK=32 staging layout, R12 core)
__device__ __forceinline__ int swzA(int b) {
    return b ^ ((b >> 3) & 0x30) ^ ((b >> 2) & 0x40);
}
// swizzle for 128-B rows (m214-proven): byte ^= (row&7)<<4, row = byte>>7
__device__ __forceinline__ int swzB(int b) {
    return b ^ (((b >> 7) & 7) << 4);
}

union H16 { ushort u; _Float16 h; };

// ---------------- cast ----------------

__global__ void cast_f16(const float4* __restrict__ in, ushort4* __restrict__ o, long n4) {
    long stride = (long)gridDim.x * blockDim.x;
    for (long i = (long)blockIdx.x * blockDim.x + threadIdx.x; i < n4; i += stride) {
        float4 v = in[i];
        float vv[4] = {v.x, v.y, v.z, v.w};
        union { _Float16 f[4]; ushort4 u; } H;
        #pragma unroll
        for (int j = 0; j < 4; ++j) H.f[j] = (_Float16)vv[j];
        o[i] = H.u;
    }
}

#define GLOAD(src_, dst_) \
    __builtin_amdgcn_global_load_lds((const AS1 void*)(src_), (AS3 void*)(dst_), 16, 0, 0)

// ------- 256x256 GEMM, BK=32, 4-deep LDS pipeline (R12-proven core) -------
// MODE 0: f32 out (DOWN)   MODE 1: f16 out (UP)

#define STAGE4(pA_, pB_, kt_, buf_) do { \
    char* db_ = Lc + (buf_)*32768 + wave*1024; \
    GLOAD((pA_) + aBase + (kt_) + off0, db_); \
    GLOAD((pA_) + aBase + (kt_) + off1, db_ +  8192); \
    GLOAD((pB_) + bBase + (kt_) + off2, db_ + 16384); \
    GLOAD((pB_) + bBase + (kt_) + off3, db_ + 24576); \
  } while (0)

template <int MODE>
__global__ __launch_bounds__(512, 2) void gemm4(
    const _Float16* __restrict__ A0, const _Float16* __restrict__ B0,
    int N, int Kp, float* __restrict__ Cf, _Float16* __restrict__ Ch)
{
    __shared__ __align__(128) char Lc[131072];   // 4 bufs x 32 KB (A 16K | B 16K)
    const int tid  = threadIdx.x;
    const int lane = tid & 63;
    const int wave = tid >> 6;
    const int wr = wave >> 2, wc = wave & 3;     // wave tile 128x64

    const int gx = gridDim.x, gy = gridDim.y;
    const int nwg = gx * gy;
    const int orig = blockIdx.y * gx + blockIdx.x;
    const int q = nwg >> 3, r = nwg & 7, xcd = orig & 7, lid = orig >> 3;
    const int wg = (xcd < r ? xcd * (q + 1) : r * (q + 1) + (xcd - r) * q) + lid;
    const int bm = wg / gy, bn = wg % gy;

    int off0, off1, off2, off3;
    {
        int o[4];
        #pragma unroll
        for (int g = 0; g < 4; ++g) {
            int p = g * 8192 + tid * 16;
            int l = swzA(p);
            int row = (l >> 6) & 255;
            int col = (l & 63) >> 1;
            o[g] = row * Kp + col;
        }
        off0 = o[0]; off1 = o[1]; off2 = o[2]; off3 = o[3];
    }
    const size_t aBase = (size_t)bm * 256 * Kp;
    const size_t bBase = (size_t)bn * 256 * Kp;

    const int l15 = lane & 15, lhi = lane >> 4;
    const int pa = swzA((wr * 128 + l15) * 64 + lhi * 16);
    const int pb = swzA(16384 + (wc * 64 + l15) * 64 + lhi * 16);

    const int NT = Kp >> 5;
    f32x4 acc[8][4] = {};

    STAGE4(A0, B0, 0,  0);
    STAGE4(A0, B0, 32, 1);
    STAGE4(A0, B0, 64, 2);

    for (int t = 0; t < NT; ++t) {
        const int rem = NT - t;
        asm volatile("s_waitcnt lgkmcnt(0)" ::: "memory");
        if (rem >= 3)      asm volatile("s_waitcnt vmcnt(8)" ::: "memory");
        else if (rem == 2) asm volatile("s_waitcnt vmcnt(4)" ::: "memory");
        else               asm volatile("s_waitcnt vmcnt(0)" ::: "memory");
        BARR;

        const char* bp = Lc + (t & 3) * 32768;
        f16x8 af[8], bfv[4];
        #pragma unroll
        for (int m = 0; m < 8; ++m) af[m]  = *(const f16x8*)(bp + pa + m * 1024);
        #pragma unroll
        for (int n = 0; n < 4; ++n) bfv[n] = *(const f16x8*)(bp + pb + n * 1024);

        if (t + 3 < NT) STAGE4(A0, B0, (t + 3) << 5, (t + 3) & 3);

        asm volatile("s_waitcnt lgkmcnt(0)" ::: "memory");
        __builtin_amdgcn_sched_barrier(0);
        __builtin_amdgcn_s_setprio(1);
        #pragma unroll
        for (int m = 0; m < 8; ++m)
            #pragma unroll
            for (int n = 0; n < 4; ++n)
                acc[m][n] = __builtin_amdgcn_mfma_f32_16x16x32_f16(af[m], bfv[n], acc[m][n], 0, 0, 0);
        __builtin_amdgcn_s_setprio(0);
    }

    const int r0 = bm * 256 + wr * 128 + (lane >> 4) * 4;
    const int c0 = bn * 256 + wc * 64 + (lane & 15);
    #pragma unroll
    for (int m = 0; m < 8; ++m) {
        #pragma unroll
        for (int n = 0; n < 4; ++n) {
            #pragma unroll
            for (int rr = 0; rr < 4; ++rr) {
                const size_t idx = (size_t)(r0 + m * 16 + rr) * N + (c0 + n * 16);
                if (MODE == 0) Cf[idx] = acc[m][n][rr];
                else           Ch[idx] = (_Float16)acc[m][n][rr];
            }
        }
    }
}

// ------- 128x128 GEMM, BK=64, 256 threads, 2 blocks/CU, 2-deep (A/B: GATE) -------

#define STAGE8(pA_, pB_, kt_, buf_) do { \
    char* db_ = Lc2 + (buf_)*32768 + wave*1024; \
    GLOAD((pA_) + aBase + (kt_) + o8[0], db_); \
    GLOAD((pA_) + aBase + (kt_) + o8[1], db_ + 4096); \
    GLOAD((pA_) + aBase + (kt_) + o8[2], db_ + 8192); \
    GLOAD((pA_) + aBase + (kt_) + o8[3], db_ + 12288); \
    GLOAD((pB_) + bBase + (kt_) + o8[4], db_ + 16384); \
    GLOAD((pB_) + bBase + (kt_) + o8[5], db_ + 20480); \
    GLOAD((pB_) + bBase + (kt_) + o8[6], db_ + 24576); \
    GLOAD((pB_) + bBase + (kt_) + o8[7], db_ + 28672); \
  } while (0)

__global__ __launch_bounds__(256, 2) void gemm2(
    const _Float16* __restrict__ A0, const _Float16* __restrict__ B0,
    int N, int Kp, _Float16* __restrict__ Ch)
{
    __shared__ __align__(128) char Lc2[65536];   // 2 bufs x 32 KB (A 16K | B 16K)
    const int tid  = threadIdx.x;
    const int lane = tid & 63;
    const int wave = tid >> 6;
    const int wr = wave >> 1, wc = wave & 1;     // 2x2 waves, wave tile 64x64

    const int gx = gridDim.x, gy = gridDim.y;
    const int nwg = gx * gy;
    const int orig = blockIdx.y * gx + blockIdx.x;
    const int q = nwg >> 3, r = nwg & 7, xcd = orig & 7, lid = orig >> 3;
    const int wg = (xcd < r ? xcd * (q + 1) : r * (q + 1) + (xcd - r) * q) + lid;
    const int bm = wg / gy, bn = wg % gy;

    // staging map: linear dest p = g*4096 + tid*16 within 16KB half <- inverse-swizzled src
    int o8[8];
    #pragma unroll
    for (int g = 0; g < 8; ++g) {
        int p = (g & 3) * 4096 + tid * 16;   // position within A- or B-half
        int l = swzB(p);
        int row = (l >> 7) & 127;
        int col = (l & 127) >> 1;
        o8[g] = row * Kp + col;
    }
    const size_t aBase = (size_t)bm * 128 * Kp;
    const size_t bBase = (size_t)bn * 128 * Kp;

    const int l15 = lane & 15, lhi = lane >> 4;
    const int pa = swzB((wr * 64 + l15) * 128 + lhi * 16);
    const int pb = swzB((wc * 64 + l15) * 128 + lhi * 16);   // within B half (+16384 base)

    const int NT = Kp >> 6;    // BK=64
    f32x4 acc[4][4] = {};

    STAGE8(A0, B0, 0,  0);
    STAGE8(A0, B0, 64, 1);

    for (int t = 0; t < NT; ++t) {
        if (t + 2 <= NT - 1) asm volatile("s_waitcnt vmcnt(8)" ::: "memory");
        else if (t == NT - 2) asm volatile("s_waitcnt vmcnt(8)" ::: "memory");
        else                  asm volatile("s_waitcnt vmcnt(0)" ::: "memory");
        BARR;                                    // buf[t&1] ready for all waves

        const char* bp = Lc2 + (t & 1) * 32768;
        f16x8 af[4][2], bfv[4][2];
        #pragma unroll
        for (int m = 0; m < 4; ++m) {
            af[m][0] = *(const f16x8*)(bp + (pa ^ 0)  + m * 2048);
            af[m][1] = *(const f16x8*)(bp + (pa ^ 64) + m * 2048);
        }
        #pragma unroll
        for (int n = 0; n < 4; ++n) {
            bfv[n][0] = *(const f16x8*)(bp + 16384 + (pb ^ 0)  + n * 2048);
            bfv[n][1] = *(const f16x8*)(bp + 16384 + (pb ^ 64) + n * 2048);
        }

        asm volatile("s_waitcnt lgkmcnt(0)" ::: "memory");   // own reads done (WAR)
        BARR;                                                // all waves' reads done

        if (t + 2 < NT) STAGE8(A0, B0, (t + 2) << 6, t & 1);

        __builtin_amdgcn_sched_barrier(0);
        __builtin_amdgcn_s_setprio(1);
        #pragma unroll
        for (int m = 0; m < 4; ++m)
            #pragma unroll
            for (int n = 0; n < 4; ++n) {
                acc[m][n] = __builtin_amdgcn_mfma_f32_16x16x32_f16(af[m][0], bfv[n][0], acc[m][n], 0, 0, 0);
                acc[m][n] = __builtin_amdgcn_mfma_f32_16x16x32_f16(af[m][1], bfv[n][1], acc[m][n], 0, 0, 0);
            }
        __builtin_amdgcn_s_setprio(0);
    }

    const int r0 = bm * 128 + wr * 64 + (lane >> 4) * 4;
    const int c0 = bn * 128 + wc * 64 + (lane & 15);
    #pragma unroll
    for (int m = 0; m < 4; ++m)
        #pragma unroll
        for (int n = 0; n < 4; ++n)
            #pragma unroll
            for (int rr = 0; rr < 4; ++rr)
                Ch[(size_t)(r0 + m * 16 + rr) * N + (c0 + n * 16)] = (_Float16)acc[m][n][rr];
}

// ---- topk + exact band-recompute + fused P = mask * g * u (in place over G) ----

__global__ __launch_bounds__(256) void topk_sel(
    _Float16* __restrict__ GP, const _Float16* __restrict__ U,
    const float* __restrict__ xf, const float* __restrict__ Wgf)
{
    __shared__ ushort keys[IDIM];
    __shared__ float  xrow[HDIM];
    __shared__ unsigned char bmap[IDIM];
    __shared__ unsigned hist[256], sA_[256], sB_[256];
    __shared__ unsigned selBin, selAbove;
    __shared__ int Acnt, nbv;
    __shared__ int   bidxs[MAXB];
    __shared__ float bval[MAXB];
    __shared__ int   kflag[MAXB];

    const int tid = threadIdx.x;
    const int t = blockIdx.x;
    _Float16* grow = GP + (size_t)t * IDIM;
    const _Float16* urow = U + (size_t)t * IDIM;

    if (tid == 0) { Acnt = 0; nbv = 0; }
    for (int j = tid; j < IDIM; j += 256) {
        H16 c; c.h = grow[j];
        keys[j] = (ushort)(c.u & 0x7FFFu);
        bmap[j] = 255;
    }
    __syncthreads();

    unsigned kq = 0;
    int Krem = KKEEP;
    for (int pass = 0; pass < 2; ++pass) {
        const int shift = pass == 0 ? 7 : 0;
        const unsigned msk = pass == 0 ? 255u : 127u;
        hist[tid] = 0;
        __syncthreads();
        for (int j = tid; j < IDIM; j += 256) {
            unsigned k = keys[j];
            bool ok = (pass == 0) || ((k >> 7) == (kq >> 7));
            if (ok) atomicAdd(&hist[(k >> shift) & msk], 1u);
        }
        __syncthreads();
        sA_[tid] = hist[tid];
        __syncthreads();
        unsigned *src = sA_, *dst = sB_;
        for (int off = 1; off < 256; off <<= 1) {
            unsigned v = src[tid] + ((tid + off < 256) ? src[tid + off] : 0u);
            dst[tid] = v;
            __syncthreads();
            unsigned* tmp = src; src = dst; dst = tmp;
        }
        unsigned S  = src[tid];
        unsigned Sn = (tid < 255) ? src[tid + 1] : 0u;
        if ((int)S >= Krem && (int)Sn < Krem) { selBin = (unsigned)tid; selAbove = Sn; }
        __syncthreads();
        kq |= selBin << shift;
        Krem -= (int)selAbove;
        __syncthreads();
    }
    H16 cv; cv.u = (ushort)kq;
    const float kthf = (float)cv.h;
    const float hif = kthf + BAND;
    const float lof = kthf - BAND;

    for (int j = tid; j < IDIM; j += 256) {
        H16 c; c.u = keys[j];
        float v = (float)c.h;
        if (v > hif) atomicAdd(&Acnt, 1);
        else if (v >= lof) {
            int s = atomicAdd(&nbv, 1);
            if (s < MAXB) { bidxs[s] = j; bmap[j] = (unsigned char)s; }
        }
    }
    for (int j = tid; j < HDIM; j += 256) xrow[j] = xf[(size_t)t * HDIM + j];
    __syncthreads();

    const int nbc = nbv < MAXB ? nbv : MAXB;
    int R = KKEEP - Acnt;
    R = R < 0 ? 0 : (R > nbc ? nbc : R);

    const int wv = tid >> 6, ln = tid & 63;
    for (int j = wv; j < nbc; j += 4) {
        const float* wrow = Wgf + (size_t)bidxs[j] * HDIM;
        float s = 0.f;
        #pragma unroll 4
        for (int it = 0; it < HDIM / 64; ++it) {
            int c = it * 64 + ln;
            s = fmaf(xrow[c], wrow[c], s);
        }
        #pragma unroll
        for (int o = 32; o; o >>= 1) s += __shfl_xor(s, o);
        if (ln == 0) bval[j] = fabsf(s);
    }
    __syncthreads();

    for (int j = tid; j < nbc; j += 256) {
        int rk = 0;
        float vj = bval[j];
        for (int k = 0; k < nbc; ++k) rk += (bval[k] > vj);
        kflag[j] = (rk < R) ? 1 : 0;
    }
    __syncthreads();

    for (int j = tid; j < IDIM; j += 256) {
        float g = (float)grow[j];
        float v = fabsf(g);
        bool keep;
        unsigned char s = bmap[j];
        if (s != 255)      keep = (kflag[s] != 0);
        else if (v > hif)  keep = true;
        else if (v < lof)  keep = false;
        else               keep = (v >= kthf);
        float u = (float)urow[j];
        grow[j] = keep ? (_Float16)(g * u) : (_Float16)0.f;
    }
}

// ---------------- host ----------------

extern "C" void kernel_launch(void* const* d_in, const int* in_sizes, int n_in,
                              void* d_out, int out_size, void* d_ws, size_t ws_size,
                              hipStream_t stream) {
    const float* x  = (const float*)d_in[0];   // [T,H]
    const float* Wg = (const float*)d_in[1];   // [I,H]
    const float* Wu = (const float*)d_in[2];   // [I,H]
    const float* Wd = (const float*)d_in[3];   // [H,I]

    const size_t NE   = (size_t)T_TOK * HDIM;
    const size_t szH2 = NE * 2;

    char* ws = (char*)d_ws;
    _Float16* xh   = (_Float16*)ws;
    _Float16* Wgh  = (_Float16*)(ws + szH2);
    _Float16* Wu16 = (_Float16*)(ws + 2 * szH2);
    _Float16* Wd16 = (_Float16*)(ws + 3 * szH2);
    _Float16* G    = (_Float16*)(ws + 4 * szH2);   // [T][I] f16 gate -> P in place
    _Float16* Uc   = (_Float16*)d_out;             // per-chunk U

    const long n4 = (long)(NE / 4);
    cast_f16<<<1024, 256, 0, stream>>>((const float4*)x,  (ushort4*)xh,   n4);
    cast_f16<<<1024, 256, 0, stream>>>((const float4*)Wg, (ushort4*)Wgh,  n4);
    cast_f16<<<1024, 256, 0, stream>>>((const float4*)Wu, (ushort4*)Wu16, n4);
    cast_f16<<<1024, 256, 0, stream>>>((const float4*)Wd, (ushort4*)Wd16, n4);

    // GATE: 128^2-tile 2-blocks/CU kernel (A/B vs the 256^2 core on UP/DOWN)
    gemm2<<<dim3(T_TOK / 128, IDIM / 128), 256, 0, stream>>>(
        xh, Wgh, IDIM, HDIM, G);

    for (int c0 = 0; c0 < T_TOK; c0 += TCHK) {
        gemm4<1><<<dim3(TCHK / 256, IDIM / 256), 512, 0, stream>>>(
            xh + (size_t)c0 * HDIM, Wu16, IDIM, HDIM, nullptr, Uc);
        topk_sel<<<TCHK, 256, 0, stream>>>(
            G + (size_t)c0 * IDIM, Uc, x + (size_t)c0 * HDIM, Wg);
    }

    // DOWN: out = P @ Wd^T
    gemm4<0><<<dim3(T_TOK / 256, HDIM / 256), 512, 0, stream>>>(
        G, Wd16, HDIM, IDIM, (float*)d_out, nullptr);
}

// Round 14
// 1438.106 us; speedup vs baseline: 3.3404x; 1.0148x over previous
//
#include <hip/hip_runtime.h>

#define T_TOK 8192   // B*S tokens
#define HDIM  2048
#define IDIM  8192
#define KKEEP 4096
#define TCHK  4096   // token chunk for UP (U parks in d_out, 67 MB)
#define BAND  1.6e-3f
#define MAXB  192

typedef _Float16 f16x8 __attribute__((ext_vector_type(8)));
typedef float    f32x4 __attribute__((ext_vector_type(4)));

#define AS1 __attribute__((address_space(1)))
#define AS3 __attribute__((address_space(3)))
#define BARR asm volatile("s_barrier" ::: "memory")

// LDS permutation for 64-B rows (BK=32): bits[4:5] ^= bits[7:8], bit[6] ^= bit[8].
__device__ __forceinline__ int swzA(int b) {
    return b ^ ((b >> 3) & 0x30) ^ ((b >> 2) & 0x40);
}

union H16 { ushort u; _Float16 h; };

// ---------------- cast ----------------

__global__ void cast_f16(const float4* __restrict__ in, ushort4* __restrict__ o, long n4) {
    long stride = (long)gridDim.x * blockDim.x;
    for (long i = (long)blockIdx.x * blockDim.x + threadIdx.x; i < n4; i += stride) {
        float4 v = in[i];
        float vv[4] = {v.x, v.y, v.z, v.w};
        union { _Float16 f[4]; ushort4 u; } H;
        #pragma unroll
        for (int j = 0; j < 4; ++j) H.f[j] = (_Float16)vv[j];
        o[i] = H.u;
    }
}

#define GLOAD(src_, dst_) \
    __builtin_amdgcn_global_load_lds((const AS1 void*)(src_), (AS3 void*)(dst_), 16, 0, 0)

// ------- 256x256 GEMM, BK=32, 4-deep LDS pipeline + 1-deep fragment dbuf -------
// MODE 0: f32 out (DOWN)   MODE 1: f16 out (GATE, UP)

#define STAGE4(pA_, pB_, kt_, buf_) do { \
    char* db_ = Lc + (buf_)*32768 + wave*1024; \
    GLOAD((pA_) + aBase + (kt_) + off0, db_); \
    GLOAD((pA_) + aBase + (kt_) + off1, db_ +  8192); \
    GLOAD((pB_) + bBase + (kt_) + off2, db_ + 16384); \
    GLOAD((pB_) + bBase + (kt_) + off3, db_ + 24576); \
  } while (0)

#define RDFRAG(dstA_, dstB_, tt_) do { \
    const char* bp_ = Lc + ((tt_) & 3) * 32768; \
    _Pragma("unroll") \
    for (int m_ = 0; m_ < 8; ++m_) (dstA_)[m_] = *(const f16x8*)(bp_ + pa + m_ * 1024); \
    _Pragma("unroll") \
    for (int n_ = 0; n_ < 4; ++n_) (dstB_)[n_] = *(const f16x8*)(bp_ + pb + n_ * 1024); \
  } while (0)

// iter body: gate+publish, stage t+3, prefetch-read frags(t+1)->NXT, MFMA(t) on CUR
#define BODY(t_, curA_, curB_, nxtA_, nxtB_) do { \
    if ((t_) + 2 < NT) asm volatile("s_waitcnt vmcnt(4)" ::: "memory"); \
    else               asm volatile("s_waitcnt vmcnt(0)" ::: "memory"); \
    BARR; \
    if ((t_) + 3 < NT) STAGE4(A0, B0, ((t_) + 3) << 5, ((t_) + 3) & 3); \
    if ((t_) + 1 < NT) RDFRAG(nxtA_, nxtB_, (t_) + 1); \
    __builtin_amdgcn_s_setprio(1); \
    _Pragma("unroll") \
    for (int m_ = 0; m_ < 8; ++m_) \
      _Pragma("unroll") \
      for (int n_ = 0; n_ < 4; ++n_) \
        acc[m_][n_] = __builtin_amdgcn_mfma_f32_16x16x32_f16((curA_)[m_], (curB_)[n_], acc[m_][n_], 0, 0, 0); \
    __builtin_amdgcn_s_setprio(0); \
  } while (0)

template <int MODE>
__global__ __launch_bounds__(512, 2) void gemm4(
    const _Float16* __restrict__ A0, const _Float16* __restrict__ B0,
    int N, int Kp, float* __restrict__ Cf, _Float16* __restrict__ Ch)
{
    __shared__ __align__(128) char Lc[131072];   // 4 bufs x 32 KB (A 16K | B 16K)
    const int tid  = threadIdx.x;
    const int lane = tid & 63;
    const int wave = tid >> 6;
    const int wr = wave >> 2, wc = wave & 3;     // wave tile 128x64

    // XCD-bijective block swizzle
    const int gx = gridDim.x, gy = gridDim.y;
    const int nwg = gx * gy;
    const int orig = blockIdx.y * gx + blockIdx.x;
    const int q = nwg >> 3, r = nwg & 7, xcd = orig & 7, lid = orig >> 3;
    const int wg = (xcd < r ? xcd * (q + 1) : r * (q + 1) + (xcd - r) * q) + lid;
    const int bm = wg / gy, bn = wg % gy;

    // staging map: linear LDS dest (tid*16) <- inverse-swizzled global source
    int off0, off1, off2, off3;
    {
        int o[4];
        #pragma unroll
        for (int g = 0; g < 4; ++g) {
            int p = g * 8192 + tid * 16;
            int l = swzA(p);
            int row = (l >> 6) & 255;
            int col = (l & 63) >> 1;
            o[g] = row * Kp + col;
        }
        off0 = o[0]; off1 = o[1]; off2 = o[2]; off3 = o[3];
    }
    const size_t aBase = (size_t)bm * 256 * Kp;
    const size_t bBase = (size_t)bn * 256 * Kp;

    const int l15 = lane & 15, lhi = lane >> 4;
    const int pa = swzA((wr * 128 + l15) * 64 + lhi * 16);
    const int pb = swzA(16384 + (wc * 64 + l15) * 64 + lhi * 16);

    const int NT = Kp >> 5;                       // even for all our shapes
    f32x4 acc[8][4] = {};
    f16x8 a0f[8], b0f[4], a1f[8], b1f[4];

    // prologue: stage tiles 0,1,2; retire t0; publish; read frags(t0) -> set0
    STAGE4(A0, B0, 0,  0);
    STAGE4(A0, B0, 32, 1);
    STAGE4(A0, B0, 64, 2);
    asm volatile("s_waitcnt vmcnt(8)" ::: "memory");
    BARR;
    RDFRAG(a0f, b0f, 0);

    for (int t = 0; t < NT; t += 2) {
        BODY(t,     a0f, b0f, a1f, b1f);
        BODY(t + 1, a1f, b1f, a0f, b0f);
    }

    // epilogue; C/D layout: col = lane&15, row = (lane>>4)*4 + reg
    const int r0 = bm * 256 + wr * 128 + (lane >> 4) * 4;
    const int c0 = bn * 256 + wc * 64 + (lane & 15);
    #pragma unroll
    for (int m = 0; m < 8; ++m) {
        #pragma unroll
        for (int n = 0; n < 4; ++n) {
            #pragma unroll
            for (int rr = 0; rr < 4; ++rr) {
                const size_t idx = (size_t)(r0 + m * 16 + rr) * N + (c0 + n * 16);
                if (MODE == 0) Cf[idx] = acc[m][n][rr];
                else           Ch[idx] = (_Float16)acc[m][n][rr];
            }
        }
    }
}

// ---- topk + exact band-recompute + fused P = mask * g * u (in place over G) ----

__global__ __launch_bounds__(256) void topk_sel(
    _Float16* __restrict__ GP, const _Float16* __restrict__ U,
    const float* __restrict__ xf, const float* __restrict__ Wgf)
{
    __shared__ ushort keys[IDIM];
    __shared__ float  xrow[HDIM];
    __shared__ unsigned char bmap[IDIM];
    __shared__ unsigned hist[256], sA_[256], sB_[256];
    __shared__ unsigned selBin, selAbove;
    __shared__ int Acnt, nbv;
    __shared__ int   bidxs[MAXB];
    __shared__ float bval[MAXB];
    __shared__ int   kflag[MAXB];

    const int tid = threadIdx.x;
    const int t = blockIdx.x;
    _Float16* grow = GP + (size_t)t * IDIM;
    const _Float16* urow = U + (size_t)t * IDIM;

    if (tid == 0) { Acnt = 0; nbv = 0; }
    for (int j = tid; j < IDIM; j += 256) {
        H16 c; c.h = grow[j];
        keys[j] = (ushort)(c.u & 0x7FFFu);
        bmap[j] = 255;
    }
    __syncthreads();

    unsigned kq = 0;
    int Krem = KKEEP;
    for (int pass = 0; pass < 2; ++pass) {
        const int shift = pass == 0 ? 7 : 0;
        const unsigned msk = pass == 0 ? 255u : 127u;
        hist[tid] = 0;
        __syncthreads();
        for (int j = tid; j < IDIM; j += 256) {
            unsigned k = keys[j];
            bool ok = (pass == 0) || ((k >> 7) == (kq >> 7));
            if (ok) atomicAdd(&hist[(k >> shift) & msk], 1u);
        }
        __syncthreads();
        sA_[tid] = hist[tid];
        __syncthreads();
        unsigned *src = sA_, *dst = sB_;
        for (int off = 1; off < 256; off <<= 1) {
            unsigned v = src[tid] + ((tid + off < 256) ? src[tid + off] : 0u);
            dst[tid] = v;
            __syncthreads();
            unsigned* tmp = src; src = dst; dst = tmp;
        }
        unsigned S  = src[tid];
        unsigned Sn = (tid < 255) ? src[tid + 1] : 0u;
        if ((int)S >= Krem && (int)Sn < Krem) { selBin = (unsigned)tid; selAbove = Sn; }
        __syncthreads();
        kq |= selBin << shift;
        Krem -= (int)selAbove;
        __syncthreads();
    }
    H16 cv; cv.u = (ushort)kq;
    const float kthf = (float)cv.h;
    const float hif = kthf + BAND;
    const float lof = kthf - BAND;

    for (int j = tid; j < IDIM; j += 256) {
        H16 c; c.u = keys[j];
        float v = (float)c.h;
        if (v > hif) atomicAdd(&Acnt, 1);
        else if (v >= lof) {
            int s = atomicAdd(&nbv, 1);
            if (s < MAXB) { bidxs[s] = j; bmap[j] = (unsigned char)s; }
        }
    }
    for (int j = tid; j < HDIM; j += 256) xrow[j] = xf[(size_t)t * HDIM + j];
    __syncthreads();

    const int nbc = nbv < MAXB ? nbv : MAXB;
    int R = KKEEP - Acnt;
    R = R < 0 ? 0 : (R > nbc ? nbc : R);

    const int wv = tid >> 6, ln = tid & 63;
    for (int j = wv; j < nbc; j += 4) {
        const float* wrow = Wgf + (size_t)bidxs[j] * HDIM;
        float s = 0.f;
        #pragma unroll 4
        for (int it = 0; it < HDIM / 64; ++it) {
            int c = it * 64 + ln;
            s = fmaf(xrow[c], wrow[c], s);
        }
        #pragma unroll
        for (int o = 32; o; o >>= 1) s += __shfl_xor(s, o);
        if (ln == 0) bval[j] = fabsf(s);
    }
    __syncthreads();

    for (int j = tid; j < nbc; j += 256) {
        int rk = 0;
        float vj = bval[j];
        for (int k = 0; k < nbc; ++k) rk += (bval[k] > vj);
        kflag[j] = (rk < R) ? 1 : 0;
    }
    __syncthreads();

    for (int j = tid; j < IDIM; j += 256) {
        float g = (float)grow[j];
        float v = fabsf(g);
        bool keep;
        unsigned char s = bmap[j];
        if (s != 255)      keep = (kflag[s] != 0);
        else if (v > hif)  keep = true;
        else if (v < lof)  keep = false;
        else               keep = (v >= kthf);
        float u = (float)urow[j];
        grow[j] = keep ? (_Float16)(g * u) : (_Float16)0.f;
    }
}

// ---------------- host ----------------

extern "C" void kernel_launch(void* const* d_in, const int* in_sizes, int n_in,
                              void* d_out, int out_size, void* d_ws, size_t ws_size,
                              hipStream_t stream) {
    const float* x  = (const float*)d_in[0];   // [T,H]
    const float* Wg = (const float*)d_in[1];   // [I,H]
    const float* Wu = (const float*)d_in[2];   // [I,H]
    const float* Wd = (const float*)d_in[3];   // [H,I]

    const size_t NE   = (size_t)T_TOK * HDIM;
    const size_t szH2 = NE * 2;

    char* ws = (char*)d_ws;
    _Float16* xh   = (_Float16*)ws;
    _Float16* Wgh  = (_Float16*)(ws + szH2);
    _Float16* Wu16 = (_Float16*)(ws + 2 * szH2);
    _Float16* Wd16 = (_Float16*)(ws + 3 * szH2);
    _Float16* G    = (_Float16*)(ws + 4 * szH2);   // [T][I] f16 gate -> P in place
    _Float16* Uc   = (_Float16*)d_out;             // per-chunk U

    const long n4 = (long)(NE / 4);
    cast_f16<<<1024, 256, 0, stream>>>((const float4*)x,  (ushort4*)xh,   n4);
    cast_f16<<<1024, 256, 0, stream>>>((const float4*)Wg, (ushort4*)Wgh,  n4);
    cast_f16<<<1024, 256, 0, stream>>>((const float4*)Wu, (ushort4*)Wu16, n4);
    cast_f16<<<1024, 256, 0, stream>>>((const float4*)Wd, (ushort4*)Wd16, n4);

    // GATE: full-size 1-pass f16 gate
    gemm4<1><<<dim3(T_TOK / 256, IDIM / 256), 512, 0, stream>>>(
        xh, Wgh, IDIM, HDIM, nullptr, G);

    for (int c0 = 0; c0 < T_TOK; c0 += TCHK) {
        gemm4<1><<<dim3(TCHK / 256, IDIM / 256), 512, 0, stream>>>(
            xh + (size_t)c0 * HDIM, Wu16, IDIM, HDIM, nullptr, Uc);
        topk_sel<<<TCHK, 256, 0, stream>>>(
            G + (size_t)c0 * IDIM, Uc, x + (size_t)c0 * HDIM, Wg);
    }

    // DOWN: out = P @ Wd^T
    gemm4<0><<<dim3(T_TOK / 256, HDIM / 256), 512, 0, stream>>>(
        G, Wd16, HDIM, IDIM, (float*)d_out, nullptr);
}

// Round 15
// 1243.188 us; speedup vs baseline: 3.8641x; 1.1568x over previous
//
#include <hip/hip_runtime.h>

#define T_TOK 8192   // B*S tokens
#define HDIM  2048
#define IDIM  8192
#define KKEEP 4096
#define TCHK  4096   // token chunk for UP (U parks in d_out, 67 MB)
#define BAND  1.6e-3f
#define MAXB  192

typedef _Float16 f16x8 __attribute__((ext_vector_type(8)));
typedef float    f32x4 __attribute__((ext_vector_type(4)));
typedef ushort   u16x8 __attribute__((ext_vector_type(8)));

#define AS1 __attribute__((address_space(1)))
#define AS3 __attribute__((address_space(3)))
#define BARR asm volatile("s_barrier" ::: "memory")

// LDS permutation for 64-B rows (BK=32): bits[4:5] ^= bits[7:8], bit[6] ^= bit[8].
__device__ __forceinline__ int swzA(int b) {
    return b ^ ((b >> 3) & 0x30) ^ ((b >> 2) & 0x40);
}

union H16 { ushort u; _Float16 h; };

// ---------------- cast ----------------

__global__ void cast_f16(const float4* __restrict__ in, ushort4* __restrict__ o, long n4) {
    long stride = (long)gridDim.x * blockDim.x;
    for (long i = (long)blockIdx.x * blockDim.x + threadIdx.x; i < n4; i += stride) {
        float4 v = in[i];
        float vv[4] = {v.x, v.y, v.z, v.w};
        union { _Float16 f[4]; ushort4 u; } H;
        #pragma unroll
        for (int j = 0; j < 4; ++j) H.f[j] = (_Float16)vv[j];
        o[i] = H.u;
    }
}

#define GLOAD(src_, dst_) \
    __builtin_amdgcn_global_load_lds((const AS1 void*)(src_), (AS3 void*)(dst_), 16, 0, 0)

// ------- 256x256 GEMM, BK=32, 4-deep LDS pipeline + 1-deep fragment dbuf -------
// MODE 0: f32 out (DOWN)   MODE 1: f16 out (GATE, UP)

#define STAGE4(pA_, pB_, kt_, buf_) do { \
    char* db_ = Lc + (buf_)*32768 + wave*1024; \
    GLOAD((pA_) + aBase + (kt_) + off0, db_); \
    GLOAD((pA_) + aBase + (kt_) + off1, db_ +  8192); \
    GLOAD((pB_) + bBase + (kt_) + off2, db_ + 16384); \
    GLOAD((pB_) + bBase + (kt_) + off3, db_ + 24576); \
  } while (0)

#define RDFRAG(dstA_, dstB_, tt_) do { \
    const char* bp_ = Lc + ((tt_) & 3) * 32768; \
    _Pragma("unroll") \
    for (int m_ = 0; m_ < 8; ++m_) (dstA_)[m_] = *(const f16x8*)(bp_ + pa + m_ * 1024); \
    _Pragma("unroll") \
    for (int n_ = 0; n_ < 4; ++n_) (dstB_)[n_] = *(const f16x8*)(bp_ + pb + n_ * 1024); \
  } while (0)

// iter body: gate+publish, stage t+3, prefetch-read frags(t+1)->NXT, MFMA(t) on CUR
#define BODY(t_, curA_, curB_, nxtA_, nxtB_) do { \
    if ((t_) + 2 < NT) asm volatile("s_waitcnt vmcnt(4)" ::: "memory"); \
    else               asm volatile("s_waitcnt vmcnt(0)" ::: "memory"); \
    BARR; \
    if ((t_) + 3 < NT) STAGE4(A0, B0, ((t_) + 3) << 5, ((t_) + 3) & 3); \
    if ((t_) + 1 < NT) RDFRAG(nxtA_, nxtB_, (t_) + 1); \
    __builtin_amdgcn_s_setprio(1); \
    _Pragma("unroll") \
    for (int m_ = 0; m_ < 8; ++m_) \
      _Pragma("unroll") \
      for (int n_ = 0; n_ < 4; ++n_) \
        acc[m_][n_] = __builtin_amdgcn_mfma_f32_16x16x32_f16((curA_)[m_], (curB_)[n_], acc[m_][n_], 0, 0, 0); \
    __builtin_amdgcn_s_setprio(0); \
  } while (0)

template <int MODE>
__global__ __launch_bounds__(512, 2) void gemm4(
    const _Float16* __restrict__ A0, const _Float16* __restrict__ B0,
    int N, int Kp, float* __restrict__ Cf, _Float16* __restrict__ Ch)
{
    __shared__ __align__(128) char Lc[131072];   // 4 bufs x 32 KB (A 16K | B 16K)
    const int tid  = threadIdx.x;
    const int lane = tid & 63;
    const int wave = tid >> 6;
    const int wr = wave >> 2, wc = wave & 3;     // wave tile 128x64

    // XCD-bijective block swizzle
    const int gx = gridDim.x, gy = gridDim.y;
    const int nwg = gx * gy;
    const int orig = blockIdx.y * gx + blockIdx.x;
    const int q = nwg >> 3, r = nwg & 7, xcd = orig & 7, lid = orig >> 3;
    const int wg = (xcd < r ? xcd * (q + 1) : r * (q + 1) + (xcd - r) * q) + lid;
    const int bm = wg / gy, bn = wg % gy;

    // staging map: linear LDS dest (tid*16) <- inverse-swizzled global source
    int off0, off1, off2, off3;
    {
        int o[4];
        #pragma unroll
        for (int g = 0; g < 4; ++g) {
            int p = g * 8192 + tid * 16;
            int l = swzA(p);
            int row = (l >> 6) & 255;
            int col = (l & 63) >> 1;
            o[g] = row * Kp + col;
        }
        off0 = o[0]; off1 = o[1]; off2 = o[2]; off3 = o[3];
    }
    const size_t aBase = (size_t)bm * 256 * Kp;
    const size_t bBase = (size_t)bn * 256 * Kp;

    const int l15 = lane & 15, lhi = lane >> 4;
    const int pa = swzA((wr * 128 + l15) * 64 + lhi * 16);
    const int pb = swzA(16384 + (wc * 64 + l15) * 64 + lhi * 16);

    const int NT = Kp >> 5;                       // even for all our shapes
    f32x4 acc[8][4] = {};
    f16x8 a0f[8], b0f[4], a1f[8], b1f[4];

    STAGE4(A0, B0, 0,  0);
    STAGE4(A0, B0, 32, 1);
    STAGE4(A0, B0, 64, 2);
    asm volatile("s_waitcnt vmcnt(8)" ::: "memory");
    BARR;
    RDFRAG(a0f, b0f, 0);

    for (int t = 0; t < NT; t += 2) {
        BODY(t,     a0f, b0f, a1f, b1f);
        BODY(t + 1, a1f, b1f, a0f, b0f);
    }

    const int r0 = bm * 256 + wr * 128 + (lane >> 4) * 4;
    const int c0 = bn * 256 + wc * 64 + (lane & 15);
    #pragma unroll
    for (int m = 0; m < 8; ++m) {
        #pragma unroll
        for (int n = 0; n < 4; ++n) {
            #pragma unroll
            for (int rr = 0; rr < 4; ++rr) {
                const size_t idx = (size_t)(r0 + m * 16 + rr) * N + (c0 + n * 16);
                if (MODE == 0) Cf[idx] = acc[m][n][rr];
                else           Ch[idx] = (_Float16)acc[m][n][rr];
            }
        }
    }
}

// ---- topk + exact band-recompute + fused P = mask * g * u — VECTORIZED ----

__global__ __launch_bounds__(256) void topk_sel(
    _Float16* __restrict__ GP, const _Float16* __restrict__ U,
    const float* __restrict__ xf, const float* __restrict__ Wgf)
{
    __shared__ ushort keys[IDIM];
    __shared__ float  xrow[HDIM];
    __shared__ unsigned char bmap[IDIM];
    __shared__ unsigned hist[256], sA_[256], sB_[256];
    __shared__ unsigned selBin, selAbove;
    __shared__ int Acnt, nbv;
    __shared__ int   bidxs[MAXB];
    __shared__ float bval[MAXB];
    __shared__ int   kflag[MAXB];

    const int tid = threadIdx.x;
    const int t = blockIdx.x;
    _Float16* grow = GP + (size_t)t * IDIM;
    const _Float16* urow = U + (size_t)t * IDIM;

    if (tid == 0) { Acnt = 0; nbv = 0; }
    // keys staging: u16x8 vector loads (16 B/lane), b128 LDS stores
    for (int j8 = tid * 8; j8 < IDIM; j8 += 2048) {
        u16x8 v = *(const u16x8*)(grow + j8);
        u16x8 k;
        #pragma unroll
        for (int e = 0; e < 8; ++e) k[e] = (ushort)(v[e] & 0x7FFFu);
        *(u16x8*)(keys + j8) = k;
    }
    // bmap init: 4 B granularity
    for (int j4 = tid; j4 < IDIM / 4; j4 += 256)
        ((unsigned*)bmap)[j4] = 0xFFFFFFFFu;
    // x row -> LDS (float4)
    for (int j4 = tid * 4; j4 < HDIM; j4 += 1024)
        *(float4*)(xrow + j4) = *(const float4*)(xf + (size_t)t * HDIM + j4);
    __syncthreads();

    // 2-pass radix select on f16 magnitude bits
    unsigned kq = 0;
    int Krem = KKEEP;
    for (int pass = 0; pass < 2; ++pass) {
        const int shift = pass == 0 ? 7 : 0;
        const unsigned msk = pass == 0 ? 255u : 127u;
        hist[tid] = 0;
        __syncthreads();
        for (int j8 = tid * 8; j8 < IDIM; j8 += 2048) {
            u16x8 kv = *(const u16x8*)(keys + j8);
            #pragma unroll
            for (int e = 0; e < 8; ++e) {
                unsigned k = kv[e];
                bool ok = (pass == 0) || ((k >> 7) == (kq >> 7));
                if (ok) atomicAdd(&hist[(k >> shift) & msk], 1u);
            }
        }
        __syncthreads();
        sA_[tid] = hist[tid];
        __syncthreads();
        unsigned *src = sA_, *dst = sB_;
        for (int off = 1; off < 256; off <<= 1) {
            unsigned v = src[tid] + ((tid + off < 256) ? src[tid + off] : 0u);
            dst[tid] = v;
            __syncthreads();
            unsigned* tmp = src; src = dst; dst = tmp;
        }
        unsigned S  = src[tid];
        unsigned Sn = (tid < 255) ? src[tid + 1] : 0u;
        if ((int)S >= Krem && (int)Sn < Krem) { selBin = (unsigned)tid; selAbove = Sn; }
        __syncthreads();
        kq |= selBin << shift;
        Krem -= (int)selAbove;
        __syncthreads();
    }
    H16 cv; cv.u = (ushort)kq;
    const float kthf = (float)cv.h;
    const float hif = kthf + BAND;
    const float lof = kthf - BAND;

    // above-band count + band collection (vectorized key reads)
    for (int j8 = tid * 8; j8 < IDIM; j8 += 2048) {
        u16x8 kv = *(const u16x8*)(keys + j8);
        #pragma unroll
        for (int e = 0; e < 8; ++e) {
            H16 c; c.u = kv[e];
            float v = (float)c.h;
            if (v > hif) atomicAdd(&Acnt, 1);
            else if (v >= lof) {
                int s = atomicAdd(&nbv, 1);
                if (s < MAXB) { bidxs[s] = j8 + e; bmap[j8 + e] = (unsigned char)s; }
            }
        }
    }
    __syncthreads();

    const int nbc = nbv < MAXB ? nbv : MAXB;
    int R = KKEEP - Acnt;
    R = R < 0 ? 0 : (R > nbc ? nbc : R);

    // exact f32 dots for band members (one wave per member, float4 ILP)
    const int wv = tid >> 6, ln = tid & 63;
    for (int j = wv; j < nbc; j += 4) {
        const float* wrow = Wgf + (size_t)bidxs[j] * HDIM;
        float s = 0.f;
        #pragma unroll
        for (int it = 0; it < HDIM / 256; ++it) {       // 8 iters, 16 B/lane
            const int c = it * 256 + ln * 4;
            float4 w = *(const float4*)(wrow + c);
            float4 xv = *(const float4*)(xrow + c);
            s = fmaf(xv.x, w.x, s);
            s = fmaf(xv.y, w.y, s);
            s = fmaf(xv.z, w.z, s);
            s = fmaf(xv.w, w.w, s);
        }
        #pragma unroll
        for (int o = 32; o; o >>= 1) s += __shfl_xor(s, o);
        if (ln == 0) bval[j] = fabsf(s);
    }
    __syncthreads();

    // keep the R largest exact band values
    for (int j = tid; j < nbc; j += 256) {
        int rk = 0;
        float vj = bval[j];
        for (int k = 0; k < nbc; ++k) rk += (bval[k] > vj);
        kflag[j] = (rk < R) ? 1 : 0;
    }
    __syncthreads();

    // write P = keep ? g*u : 0 (vectorized read-modify-write)
    for (int j8 = tid * 8; j8 < IDIM; j8 += 2048) {
        u16x8 g8 = *(const u16x8*)(grow + j8);
        u16x8 u8 = *(const u16x8*)(urow + j8);
        u16x8 p8;
        #pragma unroll
        for (int e = 0; e < 8; ++e) {
            H16 cg; cg.u = g8[e];
            H16 cu; cu.u = u8[e];
            float g = (float)cg.h;
            float v = fabsf(g);
            bool keep;
            unsigned char s = bmap[j8 + e];
            if (s != 255)      keep = (kflag[s] != 0);
            else if (v > hif)  keep = true;
            else if (v < lof)  keep = false;
            else               keep = (v >= kthf);
            H16 cp; cp.h = keep ? (_Float16)(g * (float)cu.h) : (_Float16)0.f;
            p8[e] = cp.u;
        }
        *(u16x8*)(grow + j8) = p8;
    }
}

// ---------------- host ----------------

extern "C" void kernel_launch(void* const* d_in, const int* in_sizes, int n_in,
                              void* d_out, int out_size, void* d_ws, size_t ws_size,
                              hipStream_t stream) {
    const float* x  = (const float*)d_in[0];   // [T,H]
    const float* Wg = (const float*)d_in[1];   // [I,H]
    const float* Wu = (const float*)d_in[2];   // [I,H]
    const float* Wd = (const float*)d_in[3];   // [H,I]

    const size_t NE   = (size_t)T_TOK * HDIM;
    const size_t szH2 = NE * 2;

    char* ws = (char*)d_ws;
    _Float16* xh   = (_Float16*)ws;
    _Float16* Wgh  = (_Float16*)(ws + szH2);
    _Float16* Wu16 = (_Float16*)(ws + 2 * szH2);
    _Float16* Wd16 = (_Float16*)(ws + 3 * szH2);
    _Float16* G    = (_Float16*)(ws + 4 * szH2);   // [T][I] f16 gate -> P in place
    _Float16* Uc   = (_Float16*)d_out;             // per-chunk U

    const long n4 = (long)(NE / 4);
    cast_f16<<<1024, 256, 0, stream>>>((const float4*)x,  (ushort4*)xh,   n4);
    cast_f16<<<1024, 256, 0, stream>>>((const float4*)Wg, (ushort4*)Wgh,  n4);
    cast_f16<<<1024, 256, 0, stream>>>((const float4*)Wu, (ushort4*)Wu16, n4);
    cast_f16<<<1024, 256, 0, stream>>>((const float4*)Wd, (ushort4*)Wd16, n4);

    // GATE: full-size 1-pass f16 gate
    gemm4<1><<<dim3(T_TOK / 256, IDIM / 256), 512, 0, stream>>>(
        xh, Wgh, IDIM, HDIM, nullptr, G);

    for (int c0 = 0; c0 < T_TOK; c0 += TCHK) {
        gemm4<1><<<dim3(TCHK / 256, IDIM / 256), 512, 0, stream>>>(
            xh + (size_t)c0 * HDIM, Wu16, IDIM, HDIM, nullptr, Uc);
        topk_sel<<<TCHK, 256, 0, stream>>>(
            G + (size_t)c0 * IDIM, Uc, x + (size_t)c0 * HDIM, Wg);
    }

    // DOWN: out = P @ Wd^T
    gemm4<0><<<dim3(T_TOK / 256, HDIM / 256), 512, 0, stream>>>(
        G, Wd16, HDIM, IDIM, (float*)d_out, nullptr);
}